// Round 1
// 79.544 us; speedup vs baseline: 1.0312x; 1.0312x over previous
//
#include <hip/hip_runtime.h>

// LinkPredictor: q[i,j] = relu(z_i@W1a + z_j@W1b + b1) @ W2 + b2, N=1024, D=128.
// R2 theory: pair_kernel was 256 blocks = 1 block/CU = 1 wave/SIMD -> LDS latency
// fully exposed (no co-resident waves). Compute floor is ~5 us VALU / ~5 us LDS.
// Changes: TJ 64->32 (512 blocks, 2 blocks/CU, 2 waves/SIMD), micro-tile 4x2,
// W2 via uniform scalar loads (SGPR fma operand, DS pipe freed), full d-unroll.
// proj_kernel: 4 rows/block (W1 L2 traffic 134MB -> 33MB), z rows wave-uniform.

#define NN 1024
#define DD 128
#define TI 64
#define TJ 32
#define PAD 132   // LDS row pitch in floats: bank step 4 -> 2-way alias only (free, m136)

__global__ __launch_bounds__(256) void proj_kernel(
    const float* __restrict__ z,
    const float* __restrict__ W1,
    const float* __restrict__ b1,
    float* __restrict__ pic,
    float* __restrict__ pj)
{
    const int i0 = blockIdx.x * 4;          // 4 rows per block, grid = 256
    const int t = threadIdx.x;
    const int half = t >> 7;                // wave-uniform: waves 0-1 -> pic, 2-3 -> pj
    const int d = t & (DD - 1);
    const float* __restrict__ Wcol = W1 + half * DD * DD + d;
    const float* __restrict__ z0 = z + i0 * DD;   // block-uniform -> scalar loads

    float a0 = 0.f, a1 = 0.f, a2 = 0.f, a3 = 0.f;
    #pragma unroll 8
    for (int k = 0; k < DD; ++k) {
        const float w = Wcol[k * DD];       // coalesced vector load (512B/half-wavegroup)
        a0 = fmaf(z0[k], w, a0);            // z0[*] uniform -> s_load, K$-cached
        a1 = fmaf(z0[DD + k], w, a1);
        a2 = fmaf(z0[2 * DD + k], w, a2);
        a3 = fmaf(z0[3 * DD + k], w, a3);
    }
    if (half == 0) {
        const float bb = b1[d];             // fold bias into pic
        pic[(i0 + 0) * DD + d] = a0 + bb;
        pic[(i0 + 1) * DD + d] = a1 + bb;
        pic[(i0 + 2) * DD + d] = a2 + bb;
        pic[(i0 + 3) * DD + d] = a3 + bb;
    } else {
        pj[(i0 + 0) * DD + d] = a0;
        pj[(i0 + 1) * DD + d] = a1;
        pj[(i0 + 2) * DD + d] = a2;
        pj[(i0 + 3) * DD + d] = a3;
    }
}

__global__ __launch_bounds__(256, 2) void pair_kernel(
    const float* __restrict__ pic,
    const float* __restrict__ pj,
    const float* __restrict__ W2,
    const float* __restrict__ b2,
    float* __restrict__ out)
{
    __shared__ float a_s[TI * PAD];   // 33.0 KB
    __shared__ float b_s[TJ * PAD];   // 16.5 KB  -> 49.5 KB total, 2-3 blocks/CU

    const int t  = threadIdx.x;
    const int bi = blockIdx.x;
    const int bj = blockIdx.y;

    // Stage tiles, coalesced float4. A: 64x128 = 2048 float4 (8/thread); B: 1024 (4/thread).
    const float4* __restrict__ srcA = (const float4*)(pic + bi * TI * DD);
    const float4* __restrict__ srcB = (const float4*)(pj + bj * TJ * DD);
    #pragma unroll
    for (int u = 0; u < 8; ++u) {
        int f   = t + 256 * u;        // [0, 2048)
        int row = f >> 5;             // 32 float4 per row
        int c4  = f & 31;
        *(float4*)&a_s[row * PAD + c4 * 4] = srcA[f];
    }
    #pragma unroll
    for (int u = 0; u < 4; ++u) {
        int f   = t + 256 * u;        // [0, 1024)
        int row = f >> 5;
        int c4  = f & 31;
        *(float4*)&b_s[row * PAD + c4 * 4] = srcB[f];
    }
    __syncthreads();

    const int tx = t & 15;   // j-lane
    const int ty = t >> 4;   // i-lane
    // i = bi*64 + ty + 16*ii (ii<4), j = bj*32 + tx + 16*jj (jj<2).
    // bv: 16 lanes stride PAD floats -> banks step 4 -> 2-way alias (free).
    // av: 16-lane broadcast per ty, 4 distinct addrs in disjoint bank groups.
    const float* ap = a_s + ty * PAD;
    const float* bp = b_s + tx * PAD;

    float acc[4][2];
    #pragma unroll
    for (int ii = 0; ii < 4; ++ii)
        #pragma unroll
        for (int jj = 0; jj < 2; ++jj) acc[ii][jj] = 0.f;

    #pragma unroll
    for (int d = 0; d < DD; d += 4) {
        // W2+d is wave-uniform -> s_load_dwordx4; fma takes the SGPR operand
        // directly (1 SGPR/VALU-op allowed), DS pipe carries only av/bv.
        const float4 w4 = *(const float4*)(W2 + d);
        float4 av[4], bv[2];
        #pragma unroll
        for (int ii = 0; ii < 4; ++ii) av[ii] = *(const float4*)(ap + ii * 16 * PAD + d);
        #pragma unroll
        for (int jj = 0; jj < 2; ++jj) bv[jj] = *(const float4*)(bp + jj * 16 * PAD + d);

        #pragma unroll
        for (int ii = 0; ii < 4; ++ii) {
            const float ax = av[ii].x, ay = av[ii].y, az = av[ii].z, aw = av[ii].w;
            #pragma unroll
            for (int jj = 0; jj < 2; ++jj) {
                acc[ii][jj] = fmaf(fmaxf(ax + bv[jj].x, 0.f), w4.x, acc[ii][jj]);
                acc[ii][jj] = fmaf(fmaxf(ay + bv[jj].y, 0.f), w4.y, acc[ii][jj]);
                acc[ii][jj] = fmaf(fmaxf(az + bv[jj].z, 0.f), w4.z, acc[ii][jj]);
                acc[ii][jj] = fmaf(fmaxf(aw + bv[jj].w, 0.f), w4.w, acc[ii][jj]);
            }
        }
    }

    const float bb = b2[0];
    #pragma unroll
    for (int ii = 0; ii < 4; ++ii) {
        const int i = bi * TI + ty + ii * 16;
        #pragma unroll
        for (int jj = 0; jj < 2; ++jj) {
            const int j = bj * TJ + tx + jj * 16;
            out[(size_t)i * NN + j] = acc[ii][jj] + bb;
        }
    }
}

extern "C" void kernel_launch(void* const* d_in, const int* in_sizes, int n_in,
                              void* d_out, int out_size, void* d_ws, size_t ws_size,
                              hipStream_t stream)
{
    const float* z  = (const float*)d_in[0];   // [1024,128]
    const float* W1 = (const float*)d_in[1];   // [256,128] row-major
    const float* b1 = (const float*)d_in[2];   // [128]
    const float* W2 = (const float*)d_in[3];   // [128]
    const float* b2 = (const float*)d_in[4];   // [1]
    float* out = (float*)d_out;                // [1024*1024]

    float* pic = (float*)d_ws;                 // [1024,128] fp32 (bias folded)
    float* pj  = pic + NN * DD;                // [1024,128] fp32

    proj_kernel<<<NN / 4, 256, 0, stream>>>(z, W1, b1, pic, pj);

    dim3 grid(NN / TI, NN / TJ);               // (16, 32) = 512 blocks, 2 blocks/CU
    pair_kernel<<<grid, 256, 0, stream>>>(pic, pj, W2, b2, out);
}